// Round 2
// baseline (2645.284 us; speedup 1.0000x reference)
//
#include <hip/hip_runtime.h>
#include <hip/hip_bf16.h>
#include <math.h>

// Problem constants (from reference)
#define NTOK 4096
#define DIN  1024
#define H1D  2048
#define H2D  1024
#define NE   8
#define KSEL 2      // TOPK
#define HCH  512    // H1 column chunk (4 chunks) to keep workspace ~51 MB

// GEMM tiling
constexpr int BM = 128, BN = 128, BK = 8;
constexpr int MAX_TILES = NTOK / BM; // 32 (worst case: all tokens on one expert)

// ---------------------------------------------------------------------------
// Kernel 0: zero the per-expert counters (ws is poisoned 0xAA every call)
// ---------------------------------------------------------------------------
__global__ void zero_counts(int* counts) {
    if (threadIdx.x < NE) counts[threadIdx.x] = 0;
}

// ---------------------------------------------------------------------------
// Kernel 1: top-2 gate selection, renormalization, g output, expert bucketing
// ---------------------------------------------------------------------------
__global__ void topk_gate(const float* __restrict__ gates,
                          float* __restrict__ g_out,    // [NTOK][NE]
                          int* __restrict__ counts,     // [NE]
                          int* __restrict__ bucket,     // [NE][NTOK] pair ids
                          int* __restrict__ tke,        // [NTOK][2] expert ids
                          float* __restrict__ tkg)      // [NTOK][2] gates
{
    int n = blockIdx.x * blockDim.x + threadIdx.x;
    if (n >= NTOK) return;

    float v[NE];
#pragma unroll
    for (int e = 0; e < NE; ++e) v[e] = gates[n * NE + e];

    int i1 = 0; float v1 = v[0];
#pragma unroll
    for (int e = 1; e < NE; ++e) if (v[e] > v1) { v1 = v[e]; i1 = e; }
    int i2 = -1; float v2 = -1e30f;
#pragma unroll
    for (int e = 0; e < NE; ++e) if (e != i1 && v[e] > v2) { v2 = v[e]; i2 = e; }

    float s = v1 + v2 + 1e-10f;
    float g1 = v1 / s, g2 = v2 / s;

#pragma unroll
    for (int e = 0; e < NE; ++e) {
        float gv = 0.f;
        if (e == i1) gv = g1;
        if (e == i2) gv = g2;
        g_out[n * NE + e] = gv;
    }
    tke[n * 2 + 0] = i1; tkg[n * 2 + 0] = g1;
    tke[n * 2 + 1] = i2; tkg[n * 2 + 1] = g2;

    int s1 = atomicAdd(&counts[i1], 1);
    bucket[i1 * NTOK + s1] = n * 2 + 0;     // pair id p = n*2+k
    int s2 = atomicAdd(&counts[i2], 1);
    bucket[i2 * NTOK + s2] = n * 2 + 1;
}

// ---------------------------------------------------------------------------
// Grouped GEMM, 128x128 tile, BK=8, 256 threads, 8x8 micro-tile, fp32.
//   rows gathered from bucket[e]; A row = entry >> SHIFT.
//   RELU_BIAS: C = relu(acc + bias)     (layer 1)
//   ACCUM:     C += acc                 (layer 2, chunks > 0)
//   neither:   C = acc                  (layer 2, chunk 0)
// ---------------------------------------------------------------------------
template<int SHIFT, bool RELU_BIAS, bool ACCUM>
__global__ __launch_bounds__(256)
void grouped_gemm(const float* __restrict__ A, int lda,
                  const float* __restrict__ W, size_t wstride_e, int ldw,
                  const float* __restrict__ bias, int bstride_e,
                  float* __restrict__ C, int ldc,
                  const int* __restrict__ bucket,
                  const int* __restrict__ counts,
                  int K)
{
    const int e    = blockIdx.x / MAX_TILES;
    const int tile = blockIdx.x % MAX_TILES;
    const int cnt  = counts[e];
    const int row0 = tile * BM;
    if (row0 >= cnt) return;                 // uniform per block
    const int col0 = blockIdx.y * BN;

    __shared__ float As[BK][BM];
    __shared__ float Bs[BK][BN];
    __shared__ int   rowmap[BM];

    const int tid = threadIdx.x;
    if (tid < BM) {
        int r = row0 + tid;
        rowmap[tid] = (r < cnt) ? bucket[e * NTOK + r] : -1;
    }
    __syncthreads();

    const int tx = tid & 15;   // 16 column groups of 8
    const int ty = tid >> 4;   // 16 row groups of 8

    float acc[8][8];
#pragma unroll
    for (int i = 0; i < 8; ++i)
#pragma unroll
        for (int j = 0; j < 8; ++j) acc[i][j] = 0.f;

    // A-load: 2 threads per row, float4 each (BK=8)
    const int a_row = tid >> 1;
    const int a_k   = (tid & 1) * 4;
    const int aentry = rowmap[a_row];
    const float* aptr = A + ((aentry >= 0) ? (size_t)(aentry >> SHIFT) * lda : 0) + a_k;

    // B-load: 32 threads per k-row, float4 each
    const int b_k   = tid >> 5;
    const int b_col = (tid & 31) * 4;
    const float* wptr = W + (size_t)e * wstride_e + (size_t)b_k * ldw + col0 + b_col;

    for (int k0 = 0; k0 < K; k0 += BK) {
        float4 av = make_float4(0.f, 0.f, 0.f, 0.f);
        if (aentry >= 0) av = *(const float4*)(aptr + k0);
        float4 bv = *(const float4*)(wptr + (size_t)k0 * ldw);

        __syncthreads();  // previous iteration's LDS reads done
        As[a_k + 0][a_row] = av.x;
        As[a_k + 1][a_row] = av.y;
        As[a_k + 2][a_row] = av.z;
        As[a_k + 3][a_row] = av.w;
        *(float4*)&Bs[b_k][b_col] = bv;
        __syncthreads();

#pragma unroll
        for (int k = 0; k < BK; ++k) {
            float4 a0 = *(const float4*)&As[k][ty * 8];
            float4 a1 = *(const float4*)&As[k][ty * 8 + 4];
            float4 b0 = *(const float4*)&Bs[k][tx * 8];
            float4 b1 = *(const float4*)&Bs[k][tx * 8 + 4];
            float am[8] = {a0.x, a0.y, a0.z, a0.w, a1.x, a1.y, a1.z, a1.w};
            float bm[8] = {b0.x, b0.y, b0.z, b0.w, b1.x, b1.y, b1.z, b1.w};
#pragma unroll
            for (int i = 0; i < 8; ++i)
#pragma unroll
                for (int j = 0; j < 8; ++j)
                    acc[i][j] = fmaf(am[i], bm[j], acc[i][j]);
        }
    }

    float bb[8];
    if (RELU_BIAS) {
        float4 bia0 = *(const float4*)&bias[(size_t)e * bstride_e + col0 + tx * 8];
        float4 bia1 = *(const float4*)&bias[(size_t)e * bstride_e + col0 + tx * 8 + 4];
        bb[0]=bia0.x; bb[1]=bia0.y; bb[2]=bia0.z; bb[3]=bia0.w;
        bb[4]=bia1.x; bb[5]=bia1.y; bb[6]=bia1.z; bb[7]=bia1.w;
    }

#pragma unroll
    for (int i = 0; i < 8; ++i) {
        int m = ty * 8 + i;
        int entry = rowmap[m];
        if (entry < 0) continue;
        float* crow = C + (size_t)entry * ldc + col0 + tx * 8;
        float o[8];
#pragma unroll
        for (int j = 0; j < 8; ++j) o[j] = acc[i][j];
        if (RELU_BIAS) {
#pragma unroll
            for (int j = 0; j < 8; ++j) o[j] = fmaxf(o[j] + bb[j], 0.f);
        }
        if (ACCUM) {
            float4 c0 = *(const float4*)crow;
            float4 c1 = *(const float4*)(crow + 4);
            o[0]+=c0.x; o[1]+=c0.y; o[2]+=c0.z; o[3]+=c0.w;
            o[4]+=c1.x; o[5]+=c1.y; o[6]+=c1.z; o[7]+=c1.w;
        }
        float4 o0 = make_float4(o[0],o[1],o[2],o[3]);
        float4 o1 = make_float4(o[4],o[5],o[6],o[7]);
        *(float4*)crow = o0;
        *(float4*)(crow + 4) = o1;
    }
}

// ---------------------------------------------------------------------------
// Final: relu(h2_pre + b2) dot W3, + b3, sigmoid, gated combine. 1 wave/token.
// ---------------------------------------------------------------------------
__global__ __launch_bounds__(256)
void final_layer(const float* __restrict__ h2,   // [NTOK*KSEL][H2D] pre-activation
                 const float* __restrict__ b2,   // [NE][H2D]
                 const float* __restrict__ W3,   // [NE][H2D]
                 const float* __restrict__ b3,   // [NE]
                 const int* __restrict__ tke,
                 const float* __restrict__ tkg,
                 float* __restrict__ pred)       // [NTOK]
{
    int gtid = blockIdx.x * blockDim.x + threadIdx.x;
    int n    = gtid >> 6;
    int lane = threadIdx.x & 63;
    if (n >= NTOK) return;

    float res = 0.f;
#pragma unroll
    for (int k = 0; k < KSEL; ++k) {
        int p = n * 2 + k;
        int e = tke[p];
        const float* h  = h2 + (size_t)p * H2D;
        const float* bb = b2 + (size_t)e * H2D;
        const float* w  = W3 + (size_t)e * H2D;
        float acc = 0.f;
#pragma unroll
        for (int i = 0; i < H2D / 256; ++i) {     // 4 iters of float4 per lane
            int idx = lane * 4 + i * 256;
            float4 hv = *(const float4*)(h + idx);
            float4 bv = *(const float4*)(bb + idx);
            float4 wv = *(const float4*)(w + idx);
            acc = fmaf(fmaxf(hv.x + bv.x, 0.f), wv.x, acc);
            acc = fmaf(fmaxf(hv.y + bv.y, 0.f), wv.y, acc);
            acc = fmaf(fmaxf(hv.z + bv.z, 0.f), wv.z, acc);
            acc = fmaf(fmaxf(hv.w + bv.w, 0.f), wv.w, acc);
        }
#pragma unroll
        for (int off = 32; off > 0; off >>= 1)
            acc += __shfl_xor(acc, off, 64);
        float y = 1.f / (1.f + expf(-(acc + b3[e])));
        res += tkg[p] * y;
    }
    if (lane == 0) pred[n] = res;
}

// ---------------------------------------------------------------------------
extern "C" void kernel_launch(void* const* d_in, const int* in_sizes, int n_in,
                              void* d_out, int out_size, void* d_ws, size_t ws_size,
                              hipStream_t stream)
{
    const float* x     = (const float*)d_in[0];
    const float* gates = (const float*)d_in[1];
    const float* W1    = (const float*)d_in[2];
    const float* b1    = (const float*)d_in[3];
    const float* W2    = (const float*)d_in[4];
    const float* b2    = (const float*)d_in[5];
    const float* W3    = (const float*)d_in[6];
    const float* b3    = (const float*)d_in[7];

    float* out  = (float*)d_out;
    float* pred = out;          // [NTOK]
    float* gout = out + NTOK;   // [NTOK][NE]

    // Workspace layout (~51.3 MB total):
    //   [0,      4K)   counts[NE]
    //   [4K,   132K)   bucket[NE][NTOK]
    //   [132K, 164K)   tke[NTOK][2]
    //   [164K, 196K)   tkg[NTOK][2]
    //   [1M,  1M+16.8M)  h1_chunk [8192][HCH] fp32
    //   [.. , ..+33.6M)  h2       [8192][H2D] fp32 (pre-activation)
    char* ws = (char*)d_ws;
    int*   counts = (int*)(ws);
    int*   bucket = (int*)(ws + 4096);
    int*   tke    = (int*)(ws + 4096 + 131072);
    float* tkg    = (float*)(ws + 4096 + 131072 + 32768);
    float* h1c    = (float*)(ws + (1 << 20));
    float* h2buf  = (float*)(ws + (1 << 20) + (size_t)NTOK * KSEL * HCH * 4);

    zero_counts<<<1, 64, 0, stream>>>(counts);
    topk_gate<<<NTOK / 256, 256, 0, stream>>>(gates, gout, counts, bucket, tke, tkg);

    dim3 g1(NE * MAX_TILES, HCH / BN);   // (256, 4)
    dim3 g2(NE * MAX_TILES, H2D / BN);   // (256, 8)

    for (int c = 0; c < H1D / HCH; ++c) {
        // layer 1, columns [c*HCH, (c+1)*HCH): h1c = relu(x @ W1[:,:,cols] + b1[cols])
        grouped_gemm<1, true, false><<<g1, 256, 0, stream>>>(
            x, DIN,
            W1 + c * HCH, (size_t)DIN * H1D, H1D,
            b1 + c * HCH, H1D,
            h1c, HCH,
            bucket, counts, DIN);
        // layer 2 partial: h2 (+)= h1c @ W2[rows c*HCH..+HCH, :]
        if (c == 0)
            grouped_gemm<0, false, false><<<g2, 256, 0, stream>>>(
                h1c, HCH,
                W2 + (size_t)c * HCH * H2D, (size_t)H1D * H2D, H2D,
                nullptr, 0,
                h2buf, H2D,
                bucket, counts, HCH);
        else
            grouped_gemm<0, false, true><<<g2, 256, 0, stream>>>(
                h1c, HCH,
                W2 + (size_t)c * HCH * H2D, (size_t)H1D * H2D, H2D,
                nullptr, 0,
                h2buf, H2D,
                bucket, counts, HCH);
    }

    final_layer<<<NTOK * 64 / 256, 256, 0, stream>>>(h2buf, b2, W3, b3, tke, tkg, pred);
}

// Round 3
// 706.174 us; speedup vs baseline: 3.7459x; 3.7459x over previous
//
#include <hip/hip_runtime.h>
#include <hip/hip_bf16.h>
#include <math.h>

#define NTOK 4096
#define DIN  1024
#define H1D  2048
#define H2D  1024
#define NE   8
#define KSEL 2

constexpr int BM = 128, BN = 128, BK = 32;
constexpr int MAX_TILES = NTOK / BM;  // 32

typedef __attribute__((ext_vector_type(8))) __bf16 bf16x8;
typedef __attribute__((ext_vector_type(4))) float  f32x4;

__device__ __forceinline__ ushort f2bf(float f) {
    union { float f; unsigned u; } c; c.f = f;
    unsigned u = c.u;
    return (ushort)((u + 0x7fffu + ((u >> 16) & 1u)) >> 16);   // RNE
}

// ---------------------------------------------------------------------------
__global__ void zero_init(int* counts, float* pp) {
    int i = blockIdx.x * blockDim.x + threadIdx.x;
    if (i < NE) counts[i] = 0;
    if (i < NTOK * KSEL) pp[i] = 0.f;
}

__global__ void convert_x(const float* __restrict__ x, ushort* __restrict__ xbf) {
    int i = (blockIdx.x * blockDim.x + threadIdx.x) * 4;   // grid exact
    float4 v = *(const float4*)(x + i);
    ushort4 o;
    o.x = f2bf(v.x); o.y = f2bf(v.y); o.z = f2bf(v.z); o.w = f2bf(v.w);
    *(ushort4*)(xbf + i) = o;
}

// ---------------------------------------------------------------------------
__global__ void topk_gate(const float* __restrict__ gates,
                          float* __restrict__ g_out,    // [NTOK][NE]
                          int* __restrict__ counts,
                          int* __restrict__ bucket,     // [NE][NTOK] pair ids
                          int* __restrict__ tke,        // [NTOK][2]
                          float* __restrict__ tkg)      // [NTOK][2]
{
    int n = blockIdx.x * blockDim.x + threadIdx.x;
    if (n >= NTOK) return;

    float v[NE];
#pragma unroll
    for (int e = 0; e < NE; ++e) v[e] = gates[n * NE + e];

    int i1 = 0; float v1 = v[0];
#pragma unroll
    for (int e = 1; e < NE; ++e) if (v[e] > v1) { v1 = v[e]; i1 = e; }
    int i2 = -1; float v2 = -1e30f;
#pragma unroll
    for (int e = 0; e < NE; ++e) if (e != i1 && v[e] > v2) { v2 = v[e]; i2 = e; }

    float s = v1 + v2 + 1e-10f;
    float g1 = v1 / s, g2 = v2 / s;

#pragma unroll
    for (int e = 0; e < NE; ++e) {
        float gv = 0.f;
        if (e == i1) gv = g1;
        if (e == i2) gv = g2;
        g_out[n * NE + e] = gv;
    }
    tke[n * 2 + 0] = i1; tkg[n * 2 + 0] = g1;
    tke[n * 2 + 1] = i2; tkg[n * 2 + 1] = g2;

    int s1 = atomicAdd(&counts[i1], 1);
    bucket[i1 * NTOK + s1] = n * 2 + 0;
    int s2 = atomicAdd(&counts[i2], 1);
    bucket[i2 * NTOK + s2] = n * 2 + 1;
}

// ---------------------------------------------------------------------------
// Grouped bf16-MFMA GEMM. 128x128 tile, BK=32, 4 waves (2x2 of 64x64),
// mfma_f32_16x16x32_bf16, double-buffered LDS.
//   A (bf16, global) gathered rows via global_load_lds (per-lane src addr,
//     linear LDS dest; swizzle applied by permuting the SOURCE k-chunk).
//   B (fp32 weights) reg-staged: 16 strided loads -> cvt bf16 -> 2x ds_write_b128
//     into [col][k] layout with the same XOR swizzle.
//   Swizzle: 16B-slot' = slot ^ ((line>>1)&3)  (line = row for A, col for B).
// MODE 1: C = bf16(relu(acc + b1)) -> h1      MODE 2: fused layer-3 partial dot.
// ---------------------------------------------------------------------------
template<int SHIFT, int MODE>
__global__ __launch_bounds__(256)
void moe_gemm(const ushort* __restrict__ Abf, int lda,
              const float* __restrict__ W, long wstride_e, int ldw,
              const float* __restrict__ bias, int bstr,
              const float* __restrict__ W3,      // MODE2: [NE][H2D]
              ushort* __restrict__ Cbf,          // MODE1: h1 out (bf16)
              float* __restrict__ ppart,         // MODE2: [NTOK*KSEL] partial logits
              const int* __restrict__ bucket,
              const int* __restrict__ counts,
              int K)
{
    const int e    = blockIdx.x / MAX_TILES;
    const int tile = blockIdx.x % MAX_TILES;
    const int cnt  = counts[e];
    const int row0 = tile * BM;
    if (row0 >= cnt) return;
    const int col0 = blockIdx.y * BN;

    __shared__ int rowmap[BM];
    __shared__ __align__(16) ushort smA[2][BM * BK];   // [row][32k] swizzled
    __shared__ __align__(16) ushort smB[2][BN * BK];   // [col][32k] swizzled

    const int tid = threadIdx.x;
    if (tid < BM) {
        int r = row0 + tid;
        rowmap[tid] = (r < cnt) ? bucket[e * NTOK + r] : -1;
    }
    __syncthreads();

    const int lane = tid & 63;
    const int wid  = tid >> 6;
    const int wm   = wid >> 1;   // wave row (0..1)
    const int wn   = wid & 1;    // wave col (0..1)

    // A staging: 2 x 16B chunks per thread, wave-uniform LDS base + lane*16
    const ushort* asrc[2];
    int adst[2];
#pragma unroll
    for (int i = 0; i < 2; ++i) {
        int c    = wid * 128 + i * 64 + lane;   // chunk 0..511
        int row  = c >> 2;
        int slot = c & 3;
        int sch  = slot ^ ((row >> 1) & 3);     // pre-permuted source chunk
        int entry = rowmap[row];
        int arow  = (entry >= 0) ? (entry >> SHIFT) : 0;
        asrc[i] = Abf + (size_t)arow * lda + sch * 8;
        adst[i] = (wid * 128 + i * 64) * 8;     // ushort offset of chunk base
    }

    // B staging: thread -> (col, k-half); 16 k-strided fp32 loads (coalesced
    // 256B/wave per k-row), convert, 2 x b128 swizzled writes.
    const int bcol = tid & 127;
    const int bh   = tid >> 7;
    const float* bsrc = W + (size_t)e * wstride_e + (size_t)(bh * 16) * ldw + col0 + bcol;
    const int bs0 = (2 * bh)     ^ ((bcol >> 1) & 3);
    const int bs1 = (2 * bh + 1) ^ ((bcol >> 1) & 3);

    f32x4 acc[4][4];
#pragma unroll
    for (int i = 0; i < 4; ++i)
#pragma unroll
        for (int j = 0; j < 4; ++j)
            acc[i][j] = (f32x4){0.f, 0.f, 0.f, 0.f};

    auto stage = [&](int buf, int k0) {
#pragma unroll
        for (int i = 0; i < 2; ++i)
            __builtin_amdgcn_global_load_lds(
                (const __attribute__((address_space(1))) unsigned*)(asrc[i] + k0),
                (__attribute__((address_space(3))) unsigned*)&smA[buf][adst[i]],
                16, 0, 0);
        const float* p = bsrc + (size_t)k0 * ldw;
        float v[16];
#pragma unroll
        for (int j = 0; j < 16; ++j) v[j] = p[(size_t)j * ldw];
        unsigned pk[8];
#pragma unroll
        for (int j = 0; j < 8; ++j)
            pk[j] = (unsigned)f2bf(v[2 * j]) | ((unsigned)f2bf(v[2 * j + 1]) << 16);
        *(uint4*)&smB[buf][bcol * 32 + bs0 * 8] = make_uint4(pk[0], pk[1], pk[2], pk[3]);
        *(uint4*)&smB[buf][bcol * 32 + bs1 * 8] = make_uint4(pk[4], pk[5], pk[6], pk[7]);
    };

    auto compute = [&](int buf) {
        bf16x8 a[4], b[4];
#pragma unroll
        for (int mi = 0; mi < 4; ++mi) {
            int row  = wm * 64 + mi * 16 + (lane & 15);
            int slot = (lane >> 4) ^ ((row >> 1) & 3);
            a[mi] = *(const bf16x8*)&smA[buf][row * 32 + slot * 8];
        }
#pragma unroll
        for (int ni = 0; ni < 4; ++ni) {
            int col  = wn * 64 + ni * 16 + (lane & 15);
            int slot = (lane >> 4) ^ ((col >> 1) & 3);
            b[ni] = *(const bf16x8*)&smB[buf][col * 32 + slot * 8];
        }
#pragma unroll
        for (int mi = 0; mi < 4; ++mi)
#pragma unroll
            for (int ni = 0; ni < 4; ++ni)
                acc[mi][ni] = __builtin_amdgcn_mfma_f32_16x16x32_bf16(
                    a[mi], b[ni], acc[mi][ni], 0, 0, 0);
    };

    const int nt = K / BK;
    stage(0, 0);
    __syncthreads();   // compiler drains vmcnt+lgkm before barrier
    for (int t = 0; t < nt; ++t) {
        int cur = t & 1;
        if (t + 1 < nt) stage(cur ^ 1, (t + 1) * BK);
        compute(cur);
        __syncthreads();
    }

    // ---- epilogue. C/D layout (m89-verified): col=lane&15, row=(lane>>4)*4+reg
    if (MODE == 1) {
        float bb[4];
#pragma unroll
        for (int ni = 0; ni < 4; ++ni)
            bb[ni] = bias[e * bstr + col0 + wn * 64 + ni * 16 + (lane & 15)];
#pragma unroll
        for (int mi = 0; mi < 4; ++mi) {
#pragma unroll
            for (int r = 0; r < 4; ++r) {
                int rt = wm * 64 + mi * 16 + (lane >> 4) * 4 + r;
                int entry = rowmap[rt];
                if (entry < 0) continue;
                ushort* crow = Cbf + (size_t)entry * H1D + col0;
#pragma unroll
                for (int ni = 0; ni < 4; ++ni) {
                    float val = fmaxf(acc[mi][ni][r] + bb[ni], 0.f);
                    crow[wn * 64 + ni * 16 + (lane & 15)] = f2bf(val);
                }
            }
        }
    } else {
        // fused layer 3: partial = sum_cols relu(h2+b2)*W3, one atomic per row
        float bb[4], w3l[4];
#pragma unroll
        for (int ni = 0; ni < 4; ++ni) {
            int cg = col0 + wn * 64 + ni * 16 + (lane & 15);
            bb[ni]  = bias[e * bstr + cg];
            w3l[ni] = W3[e * H2D + cg];
        }
        float* red = (float*)&smA[0][0];   // 128 rows x 32 slots = 16 KB
#pragma unroll
        for (int mi = 0; mi < 4; ++mi) {
#pragma unroll
            for (int r = 0; r < 4; ++r) {
                float s = 0.f;
#pragma unroll
                for (int ni = 0; ni < 4; ++ni)
                    s += fmaxf(acc[mi][ni][r] + bb[ni], 0.f) * w3l[ni];
                int rt = wm * 64 + mi * 16 + (lane >> 4) * 4 + r;
                red[rt * 32 + wn * 16 + (lane & 15)] = s;
            }
        }
        __syncthreads();
        if (tid < BM) {
            int entry = rowmap[tid];
            if (entry >= 0) {
                float s = 0.f;
#pragma unroll
                for (int j = 0; j < 32; ++j) s += red[tid * 32 + j];
                atomicAdd(&ppart[entry], s);
            }
        }
    }
}

// ---------------------------------------------------------------------------
__global__ void finalize(const float* __restrict__ pp, const float* __restrict__ b3,
                         const int* __restrict__ tke, const float* __restrict__ tkg,
                         float* __restrict__ pred) {
    int n = blockIdx.x * blockDim.x + threadIdx.x;
    if (n >= NTOK) return;
    float r = 0.f;
#pragma unroll
    for (int k = 0; k < KSEL; ++k) {
        int p = n * 2 + k;
        int ee = tke[p];
        float y = 1.f / (1.f + expf(-(pp[p] + b3[ee])));
        r += tkg[p] * y;
    }
    pred[n] = r;
}

// ---------------------------------------------------------------------------
extern "C" void kernel_launch(void* const* d_in, const int* in_sizes, int n_in,
                              void* d_out, int out_size, void* d_ws, size_t ws_size,
                              hipStream_t stream)
{
    const float* x     = (const float*)d_in[0];
    const float* gates = (const float*)d_in[1];
    const float* W1    = (const float*)d_in[2];
    const float* b1    = (const float*)d_in[3];
    const float* W2    = (const float*)d_in[4];
    const float* b2    = (const float*)d_in[5];
    const float* W3    = (const float*)d_in[6];
    const float* b3    = (const float*)d_in[7];

    float* out  = (float*)d_out;
    float* pred = out;          // [NTOK]
    float* gout = out + NTOK;   // [NTOK][NE]

    // ws layout (~42.5 MB): hdr ~1MB | x_bf 8MB | h1_bf 32MB
    char* ws = (char*)d_ws;
    int*    counts = (int*)(ws);
    int*    bucket = (int*)(ws + 4096);
    int*    tke    = (int*)(ws + 4096 + 131072);
    float*  tkg    = (float*)(ws + 4096 + 131072 + 32768);
    float*  ppart  = (float*)(ws + 4096 + 131072 + 65536);
    ushort* xbf    = (ushort*)(ws + (1 << 20));
    ushort* h1bf   = (ushort*)(ws + (1 << 20) + (size_t)NTOK * DIN * 2);

    zero_init<<<(NTOK * KSEL + 255) / 256, 256, 0, stream>>>(counts, ppart);
    topk_gate<<<NTOK / 256, 256, 0, stream>>>(gates, gout, counts, bucket, tke, tkg);
    convert_x<<<NTOK * DIN / 4 / 256, 256, 0, stream>>>(x, xbf);

    dim3 g1(NE * MAX_TILES, H1D / BN);   // (256, 16)
    moe_gemm<1, 1><<<g1, 256, 0, stream>>>(
        xbf, DIN, W1, (long)DIN * H1D, H1D, b1, H1D,
        nullptr, h1bf, nullptr, bucket, counts, DIN);

    dim3 g2(NE * MAX_TILES, H2D / BN);   // (256, 8)
    moe_gemm<0, 2><<<g2, 256, 0, stream>>>(
        h1bf, H1D, W2, (long)H1D * H2D, H2D, b2, H2D,
        W3, nullptr, ppart, bucket, counts, H1D);

    finalize<<<NTOK / 256, 256, 0, stream>>>(ppart, b3, tke, tkg, pred);
}

// Round 4
// 325.531 us; speedup vs baseline: 8.1260x; 2.1693x over previous
//
#include <hip/hip_runtime.h>
#include <hip/hip_bf16.h>
#include <math.h>

#define NTOK 4096
#define DIN  1024
#define H1D  2048
#define H2D  1024
#define NE   8
#define KSEL 2

constexpr int BM = 128, BN = 128, BK = 32;
constexpr int MAX_TILES = NTOK / BM;  // 32

typedef __attribute__((ext_vector_type(8))) __bf16 bf16x8;
typedef __attribute__((ext_vector_type(4))) float  f32x4;

__device__ __forceinline__ ushort f2bf(float f) {
    union { float f; unsigned u; } c; c.f = f;
    unsigned u = c.u;
    return (ushort)((u + 0x7fffu + ((u >> 16) & 1u)) >> 16);   // RNE
}

// ---------------------------------------------------------------------------
__global__ void zero_init(int* counts, float* pp) {
    int i = blockIdx.x * blockDim.x + threadIdx.x;
    if (i < NE) counts[i] = 0;
    if (i < NTOK * KSEL) pp[i] = 0.f;
}

__global__ void convert_x(const float* __restrict__ x, ushort* __restrict__ xbf) {
    int i = (blockIdx.x * blockDim.x + threadIdx.x) * 4;
    float4 v = *(const float4*)(x + i);
    ushort4 o;
    o.x = f2bf(v.x); o.y = f2bf(v.y); o.z = f2bf(v.z); o.w = f2bf(v.w);
    *(ushort4*)(xbf + i) = o;
}

// W[e][K][N] fp32  ->  Wt[e][N][K] bf16   (tiled 32x32 via LDS)
__global__ void transpose_cvt(const float* __restrict__ W, ushort* __restrict__ Wt,
                              int K, int N) {
    __shared__ float t[32][33];
    int e  = blockIdx.z;
    int n0 = blockIdx.x * 32, k0 = blockIdx.y * 32;
    int tx = threadIdx.x, ty = threadIdx.y;   // (32, 8)
    const float* Wp = W + ((size_t)e * K + k0) * N + n0;
#pragma unroll
    for (int i = 0; i < 4; ++i)
        t[ty + i * 8][tx] = Wp[(size_t)(ty + i * 8) * N + tx];
    __syncthreads();
    ushort* Wo = Wt + ((size_t)e * N + n0) * K + k0;
#pragma unroll
    for (int i = 0; i < 4; ++i)
        Wo[(size_t)(ty + i * 8) * K + tx] = f2bf(t[tx][ty + i * 8]);
}

// ---------------------------------------------------------------------------
__global__ void topk_gate(const float* __restrict__ gates,
                          float* __restrict__ g_out,
                          int* __restrict__ counts,
                          int* __restrict__ bucket,
                          int* __restrict__ tke,
                          float* __restrict__ tkg)
{
    int n = blockIdx.x * blockDim.x + threadIdx.x;
    if (n >= NTOK) return;

    float v[NE];
#pragma unroll
    for (int e = 0; e < NE; ++e) v[e] = gates[n * NE + e];

    int i1 = 0; float v1 = v[0];
#pragma unroll
    for (int e = 1; e < NE; ++e) if (v[e] > v1) { v1 = v[e]; i1 = e; }
    int i2 = -1; float v2 = -1e30f;
#pragma unroll
    for (int e = 0; e < NE; ++e) if (e != i1 && v[e] > v2) { v2 = v[e]; i2 = e; }

    float s = v1 + v2 + 1e-10f;
    float g1 = v1 / s, g2 = v2 / s;

#pragma unroll
    for (int e = 0; e < NE; ++e) {
        float gv = 0.f;
        if (e == i1) gv = g1;
        if (e == i2) gv = g2;
        g_out[n * NE + e] = gv;
    }
    tke[n * 2 + 0] = i1; tkg[n * 2 + 0] = g1;
    tke[n * 2 + 1] = i2; tkg[n * 2 + 1] = g2;

    int s1 = atomicAdd(&counts[i1], 1);
    bucket[i1 * NTOK + s1] = n * 2 + 0;
    int s2 = atomicAdd(&counts[i2], 1);
    bucket[i2 * NTOK + s2] = n * 2 + 1;
}

// ---------------------------------------------------------------------------
// Grouped bf16 MFMA GEMM. 128x128x32 tile, 4 waves (2x2 of 64x64), dbuf LDS.
// A and B both staged via global_load_lds (16B/lane, linear LDS dest,
// swizzle slot^=((line>>1)&3) applied by pre-permuting the SOURCE address).
// B comes from pre-transposed bf16 weights Wt[e][n][k].
// Grid 1D: e = b&7 (XCD-local experts), col0 = ((b>>3)/32)*128, tile=(b>>3)&31.
// MODE 1: C = bf16(relu(acc+bias)) -> Cbf.  MODE 2: fused relu+dot(W3) atomic.
// ---------------------------------------------------------------------------
template<int SHIFT, int MODE>
__global__ __launch_bounds__(256)
void moe_gemm(const ushort* __restrict__ Abf, int lda,
              const ushort* __restrict__ Wt,    // [NE][N][K] bf16
              const float* __restrict__ bias,   // [NE][N]
              int N,
              const float* __restrict__ W3,     // MODE2: [NE][H2D]
              ushort* __restrict__ Cbf,         // MODE1: [NTOK*KSEL][N]
              float* __restrict__ ppart,        // MODE2: [NTOK*KSEL]
              const int* __restrict__ bucket,
              const int* __restrict__ counts,
              int K)
{
    const int b    = blockIdx.x;
    const int e    = b & 7;                 // expert == XCD (b%8 round-robin)
    const int idx  = b >> 3;
    const int tile = idx & (MAX_TILES - 1);
    const int col0 = (idx / MAX_TILES) * BN;

    const int cnt  = counts[e];
    const int row0 = tile * BM;
    if (row0 >= cnt) return;

    __shared__ int rowmap[BM];
    __shared__ __align__(16) ushort smA[2][BM * BK];
    __shared__ __align__(16) ushort smB[2][BN * BK];

    const int tid = threadIdx.x;
    if (tid < BM) {
        int r = row0 + tid;
        rowmap[tid] = (r < cnt) ? bucket[e * NTOK + r] : -1;
    }
    __syncthreads();

    const int lane = tid & 63;
    const int wid  = tid >> 6;
    const int wm   = wid >> 1;
    const int wn   = wid & 1;

    // per-thread staging chunks: c = (wid*2+i)*64 + lane, line=c>>2, slot=c&3
    const ushort* aSrc[2];
    const ushort* bSrc[2];
    int dstOff[2];
#pragma unroll
    for (int i = 0; i < 2; ++i) {
        int c    = (wid * 2 + i) * 64 + lane;
        int line = c >> 2;
        int slot = c & 3;
        int sch  = slot ^ ((line >> 1) & 3);       // pre-permuted source slot
        dstOff[i] = c * 8;                         // ushort offset (16B chunks)
        int entry = rowmap[line];
        int arow  = (entry >= 0) ? (entry >> SHIFT) : 0;
        aSrc[i] = Abf + (size_t)arow * lda + sch * 8;
        bSrc[i] = Wt + ((size_t)e * N + col0 + line) * K + sch * 8;
    }

    f32x4 acc[4][4];
#pragma unroll
    for (int i = 0; i < 4; ++i)
#pragma unroll
        for (int j = 0; j < 4; ++j)
            acc[i][j] = (f32x4){0.f, 0.f, 0.f, 0.f};

    auto stage = [&](int buf, int k0) {
#pragma unroll
        for (int i = 0; i < 2; ++i)
            __builtin_amdgcn_global_load_lds(
                (const __attribute__((address_space(1))) unsigned*)(aSrc[i] + k0),
                (__attribute__((address_space(3))) unsigned*)&smA[buf][dstOff[i]],
                16, 0, 0);
#pragma unroll
        for (int i = 0; i < 2; ++i)
            __builtin_amdgcn_global_load_lds(
                (const __attribute__((address_space(1))) unsigned*)(bSrc[i] + k0),
                (__attribute__((address_space(3))) unsigned*)&smB[buf][dstOff[i]],
                16, 0, 0);
    };

    auto compute = [&](int buf) {
        bf16x8 a[4], bfr[4];
#pragma unroll
        for (int mi = 0; mi < 4; ++mi) {
            int row  = wm * 64 + mi * 16 + (lane & 15);
            int slot = (lane >> 4) ^ ((row >> 1) & 3);
            a[mi] = *(const bf16x8*)&smA[buf][row * 32 + slot * 8];
        }
#pragma unroll
        for (int ni = 0; ni < 4; ++ni) {
            int col  = wn * 64 + ni * 16 + (lane & 15);
            int slot = (lane >> 4) ^ ((col >> 1) & 3);
            bfr[ni] = *(const bf16x8*)&smB[buf][col * 32 + slot * 8];
        }
#pragma unroll
        for (int mi = 0; mi < 4; ++mi)
#pragma unroll
            for (int ni = 0; ni < 4; ++ni)
                acc[mi][ni] = __builtin_amdgcn_mfma_f32_16x16x32_bf16(
                    a[mi], bfr[ni], acc[mi][ni], 0, 0, 0);
    };

    const int nt = K / BK;
    stage(0, 0);
    __syncthreads();
    for (int t = 0; t < nt; ++t) {
        int cur = t & 1;
        if (t + 1 < nt) stage(cur ^ 1, (t + 1) * BK);
        compute(cur);
        __syncthreads();
    }

    // ---- epilogue. C/D layout: col=lane&15, row=(lane>>4)*4+reg
    if (MODE == 1) {
        float bb[4];
#pragma unroll
        for (int ni = 0; ni < 4; ++ni)
            bb[ni] = bias[e * N + col0 + wn * 64 + ni * 16 + (lane & 15)];
#pragma unroll
        for (int mi = 0; mi < 4; ++mi) {
#pragma unroll
            for (int r = 0; r < 4; ++r) {
                int rt = wm * 64 + mi * 16 + (lane >> 4) * 4 + r;
                int entry = rowmap[rt];
                if (entry < 0) continue;
                ushort* crow = Cbf + (size_t)entry * N + col0;
#pragma unroll
                for (int ni = 0; ni < 4; ++ni) {
                    float val = fmaxf(acc[mi][ni][r] + bb[ni], 0.f);
                    crow[wn * 64 + ni * 16 + (lane & 15)] = f2bf(val);
                }
            }
        }
    } else {
        float bb[4], w3l[4];
#pragma unroll
        for (int ni = 0; ni < 4; ++ni) {
            int cg = col0 + wn * 64 + ni * 16 + (lane & 15);
            bb[ni]  = bias[e * N + cg];
            w3l[ni] = W3[e * H2D + cg];
        }
#pragma unroll
        for (int mi = 0; mi < 4; ++mi) {
#pragma unroll
            for (int r = 0; r < 4; ++r) {
                float s = 0.f;
#pragma unroll
                for (int ni = 0; ni < 4; ++ni)
                    s += fmaxf(acc[mi][ni][r] + bb[ni], 0.f) * w3l[ni];
                // reduce over the 16 lanes of this group (they hold 16 cols)
#pragma unroll
                for (int off = 1; off < 16; off <<= 1)
                    s += __shfl_xor(s, off, 16);
                if ((lane & 15) == 0) {
                    int rt = wm * 64 + mi * 16 + (lane >> 4) * 4 + r;
                    int entry = rowmap[rt];
                    if (entry >= 0) atomicAdd(&ppart[entry], s);
                }
            }
        }
    }
}

// ---------------------------------------------------------------------------
__global__ void finalize(const float* __restrict__ pp, const float* __restrict__ b3,
                         const int* __restrict__ tke, const float* __restrict__ tkg,
                         float* __restrict__ pred) {
    int n = blockIdx.x * blockDim.x + threadIdx.x;
    if (n >= NTOK) return;
    float r = 0.f;
#pragma unroll
    for (int k = 0; k < KSEL; ++k) {
        int p = n * 2 + k;
        int ee = tke[p];
        float y = 1.f / (1.f + expf(-(pp[p] + b3[ee])));
        r += tkg[p] * y;
    }
    pred[n] = r;
}

// ---------------------------------------------------------------------------
extern "C" void kernel_launch(void* const* d_in, const int* in_sizes, int n_in,
                              void* d_out, int out_size, void* d_ws, size_t ws_size,
                              hipStream_t stream)
{
    const float* x     = (const float*)d_in[0];
    const float* gates = (const float*)d_in[1];
    const float* W1    = (const float*)d_in[2];
    const float* b1    = (const float*)d_in[3];
    const float* W2    = (const float*)d_in[4];
    const float* b2    = (const float*)d_in[5];
    const float* W3    = (const float*)d_in[6];
    const float* b3    = (const float*)d_in[7];

    float* out  = (float*)d_out;
    float* pred = out;
    float* gout = out + NTOK;

    // ws (~73 MB): hdr 1MB | xbf 8MB | h1bf 32MB | Wtbuf 32MB (shared W1t/W2t)
    char* ws = (char*)d_ws;
    int*    counts = (int*)(ws);
    int*    bucket = (int*)(ws + 4096);
    int*    tke    = (int*)(ws + 4096 + 131072);
    float*  tkg    = (float*)(ws + 4096 + 131072 + 32768);
    float*  ppart  = (float*)(ws + 4096 + 131072 + 65536);
    ushort* xbf    = (ushort*)(ws + (1 << 20));
    ushort* h1bf   = (ushort*)(ws + (1 << 20) + (size_t)NTOK * DIN * 2);
    ushort* wtbuf  = (ushort*)(ws + (1 << 20) + (size_t)NTOK * DIN * 2
                                  + (size_t)NTOK * KSEL * H1D * 2);

    zero_init<<<(NTOK * KSEL + 255) / 256, 256, 0, stream>>>(counts, ppart);
    topk_gate<<<NTOK / 256, 256, 0, stream>>>(gates, gout, counts, bucket, tke, tkg);
    convert_x<<<NTOK * DIN / 4 / 256, 256, 0, stream>>>(x, xbf);

    // W1 [e][1024][2048] -> Wt [e][2048][1024]
    transpose_cvt<<<dim3(H1D / 32, DIN / 32, NE), dim3(32, 8), 0, stream>>>(
        W1, wtbuf, DIN, H1D);
    moe_gemm<1, 1><<<NE * (H1D / BN) * MAX_TILES, 256, 0, stream>>>(
        xbf, DIN, wtbuf, b1, H1D, nullptr, h1bf, nullptr, bucket, counts, DIN);

    // W2 [e][2048][1024] -> Wt [e][1024][2048]
    transpose_cvt<<<dim3(H2D / 32, H1D / 32, NE), dim3(32, 8), 0, stream>>>(
        W2, wtbuf, H1D, H2D);
    moe_gemm<0, 2><<<NE * (H2D / BN) * MAX_TILES, 256, 0, stream>>>(
        h1bf, H1D, wtbuf, b2, H2D, W3, nullptr, ppart, bucket, counts, H1D);

    finalize<<<NTOK / 256, 256, 0, stream>>>(ppart, b3, tke, tkg, pred);
}